// Round 2
// baseline (1411.540 us; speedup 1.0000x reference)
//
#include <hip/hip_runtime.h>
#include <math.h>

#define NN 1024
#define BB 2
#define GG 64
#define LL 16
#define ND 256
#define H1 1024
#define ED 16

// ---------- fast device math ----------
__device__ __forceinline__ float fsig(float x) {
  // sigmoid(x) = 1/(1+2^(-x*log2e)); v_exp + v_rcp, ~2-3 ulp
  return __builtin_amdgcn_rcpf(1.0f + __builtin_amdgcn_exp2f(-1.44269504f * x));
}

__device__ __forceinline__ float erf_as(float x) {
  // Abramowitz-Stegun 7.1.26, branchless, |err| < 1.5e-7, full range
  float ax = fabsf(x);
  float t = __builtin_amdgcn_rcpf(fmaf(0.3275911f, ax, 1.0f));
  float p = fmaf(1.061405429f, t, -1.453152027f);
  p = fmaf(p, t, 1.421413741f);
  p = fmaf(p, t, -0.284496736f);
  p = fmaf(p, t, 0.254829592f);
  p *= t;
  float ex = __builtin_amdgcn_exp2f(-1.44269504f * ax * ax);
  float r = fmaf(-p, ex, 1.0f);
  return copysignf(r, x);
}

__device__ __forceinline__ float gelu_f(float x) {
  return 0.5f * x * (1.0f + erf_as(0.70710678118f * x));
}

// ---------- K1: exp_t, data_ligand, softplus params, nf (FFN + ct_emb + LN) ----------
// key identity: where(same, ffn(te*s), ffn(exp_t)) == ffn(exp_t) since exp_t==te*s when same.
__global__ __launch_bounds__(256) void k_nf(
    const float* __restrict__ x, const float* __restrict__ te, const int* __restrict__ ct,
    const float* __restrict__ scal, const float* __restrict__ W1, const float* __restrict__ b1,
    const float* __restrict__ W2, const float* __restrict__ b2, const float* __restrict__ ctemb,
    const float* __restrict__ lng, const float* __restrict__ lnb, const int* __restrict__ lig,
    const float* __restrict__ wsv, const float* __restrict__ w1e, const float* __restrict__ w2e,
    float* __restrict__ dl_ws, float* __restrict__ sp_ws, float* __restrict__ nf_out)
{
  __shared__ float s_exp[8 * 64];      // [p][g]
  __shared__ float s_h[H1 * 9];        // [c][p], stride 9
  __shared__ float s_z[8 * ND];        // pre-LN values [p][c]

  const int t = threadIdx.x;
  const int bid = blockIdx.x;
  const int b = bid >> 7;              // 128 blocks per batch
  const int n0 = (bid & 127) << 3;     // 8 positions per block

  // one-time: softplus'd parameter vectors for K2 (block 0 only)
  if (bid == 0 && t < 48) {
    const float* src = (t < 16) ? wsv : (t < 32 ? w1e : w2e);
    float v = src[t & 15];
    sp_ws[t] = fmaxf(v, 0.0f) + log1pf(expf(-fabsf(v)));
  }

  const int ct0 = ct[b * NN];

  // exp_t for 8 positions into LDS
  {
    const int p = t >> 5, gg = (t & 31) << 1;
    const int n = n0 + p;
    const bool same = (ct[b * NN + n] == ct0);
    const float2 tv = *(const float2*)&te[(size_t)(b * NN + n) * GG + gg];
    const float2 xv = *(const float2*)&x[(size_t)(b * NN + n) * GG + gg];
    const float2 sc = *(const float2*)&scal[gg];
    s_exp[p * 64 + gg]     = (same ? tv.x : tv.x + xv.x) * (sc.x * sc.x);
    s_exp[p * 64 + gg + 1] = (same ? tv.y : tv.y + xv.y) * (sc.y * sc.y);
  }
  __syncthreads();

  // data_ligand -> workspace
  if (t < 128) {
    const int p = t >> 4, l = t & 15;
    const int4 li = ((const int4*)lig)[l];
    const float gm0 = 0.5f * (s_exp[p * 64 + li.x] + s_exp[p * 64 + li.y]);
    const float gm1 = 0.5f * (s_exp[p * 64 + li.z] + s_exp[p * 64 + li.w]);
    dl_ws[((size_t)(b * NN + n0 + p) << 4) + l] = sqrtf(gm0 * gm1);
  }

  // GEMM1: thread t owns h-channels {t, t+256, t+512, t+768} for all 8 positions.
  // Strided ownership: s_h write inter-lane stride = 9 floats, gcd(9,32)=1 -> conflict-free;
  // W1/b1 loads are stride-1 coalesced dwords.
  float acc[8][4];
  #pragma unroll
  for (int p = 0; p < 8; ++p) { acc[p][0] = 0.f; acc[p][1] = 0.f; acc[p][2] = 0.f; acc[p][3] = 0.f; }
  for (int g = 0; g < 64; ++g) {
    const float w0 = W1[(size_t)g * H1 + t];
    const float w1 = W1[(size_t)g * H1 + t + 256];
    const float w2 = W1[(size_t)g * H1 + t + 512];
    const float w3 = W1[(size_t)g * H1 + t + 768];
    #pragma unroll
    for (int p = 0; p < 8; ++p) {
      const float e = s_exp[p * 64 + g];  // LDS broadcast
      acc[p][0] = fmaf(e, w0, acc[p][0]);
      acc[p][1] = fmaf(e, w1, acc[p][1]);
      acc[p][2] = fmaf(e, w2, acc[p][2]);
      acc[p][3] = fmaf(e, w3, acc[p][3]);
    }
  }
  {
    #pragma unroll
    for (int k = 0; k < 4; ++k) {
      const int c = t + (k << 8);
      const float bk = b1[c];
      #pragma unroll
      for (int p = 0; p < 8; ++p) {
        s_h[c * 9 + p] = gelu_f(acc[p][k] + bk);
      }
    }
  }
  __syncthreads();

  // GEMM2: thread -> (4 out-channels oc0.., 2 positions pg*2..)
  const int oc0 = (t & 63) << 2;
  const int pg = t >> 6;
  float z0[4] = {0.f, 0.f, 0.f, 0.f};
  float z1[4] = {0.f, 0.f, 0.f, 0.f};
  for (int c = 0; c < H1; ++c) {
    const float4 w = *(const float4*)&W2[(size_t)c * ND + oc0];
    const float h0 = s_h[c * 9 + (pg << 1)];        // wave-uniform -> broadcast
    const float h1 = s_h[c * 9 + (pg << 1) + 1];
    z0[0] = fmaf(h0, w.x, z0[0]); z0[1] = fmaf(h0, w.y, z0[1]);
    z0[2] = fmaf(h0, w.z, z0[2]); z0[3] = fmaf(h0, w.w, z0[3]);
    z1[0] = fmaf(h1, w.x, z1[0]); z1[1] = fmaf(h1, w.y, z1[1]);
    z1[2] = fmaf(h1, w.z, z1[2]); z1[3] = fmaf(h1, w.w, z1[3]);
  }
  {
    const float4 bb2 = *(const float4*)&b2[oc0];
    const int p0 = pg << 1;
    const int cc0 = ct[b * NN + n0 + p0];
    const int cc1 = ct[b * NN + n0 + p0 + 1];
    const float4 ce0 = *(const float4*)&ctemb[(size_t)cc0 * ND + oc0];
    const float4 ce1 = *(const float4*)&ctemb[(size_t)cc1 * ND + oc0];
    float4 o0, o1;
    o0.x = z0[0] + bb2.x + ce0.x; o0.y = z0[1] + bb2.y + ce0.y;
    o0.z = z0[2] + bb2.z + ce0.z; o0.w = z0[3] + bb2.w + ce0.w;
    o1.x = z1[0] + bb2.x + ce1.x; o1.y = z1[1] + bb2.y + ce1.y;
    o1.z = z1[2] + bb2.z + ce1.z; o1.w = z1[3] + bb2.w + ce1.w;
    *(float4*)&s_z[p0 * ND + oc0] = o0;
    *(float4*)&s_z[(p0 + 1) * ND + oc0] = o1;
  }
  __syncthreads();

  // LayerNorm: wave wv handles positions 2wv, 2wv+1
  const int wv = t >> 6, lane = t & 63;
  #pragma unroll
  for (int pp = 0; pp < 2; ++pp) {
    const int p = (wv << 1) + pp;
    const float4 v = *(const float4*)&s_z[p * ND + (lane << 2)];
    float s = v.x + v.y + v.z + v.w;
    float sq = v.x * v.x + v.y * v.y + v.z * v.z + v.w * v.w;
    #pragma unroll
    for (int off = 1; off < 64; off <<= 1) {
      s += __shfl_xor(s, off);
      sq += __shfl_xor(sq, off);
    }
    const float m = s * (1.0f / 256.0f);
    const float var = sq * (1.0f / 256.0f) - m * m;
    const float rstd = rsqrtf(var + 1e-5f);
    const float4 g4 = *(const float4*)&lng[lane << 2];
    const float4 b4 = *(const float4*)&lnb[lane << 2];
    float4 o;
    o.x = (v.x - m) * rstd * g4.x + b4.x;
    o.y = (v.y - m) * rstd * g4.y + b4.y;
    o.z = (v.z - m) * rstd * g4.z + b4.z;
    o.w = (v.w - m) * rstd * g4.w + b4.w;
    *(float4*)&nf_out[((size_t)(b * NN + n0 + p) << 8) + (lane << 2)] = o;
  }
}

// ---------- K2: edges + emb1 + emb2 ----------
// lane = j (coalesced); 8 i per block; all weights via uniform (scalar) loads.
__global__ __launch_bounds__(256, 2) void k_edges(
    const float* __restrict__ dist, const float* __restrict__ bsv,
    const float* __restrict__ b1e, const float* __restrict__ b2e,
    const float* __restrict__ Wl1, const float* __restrict__ Wl2,
    const float* __restrict__ dl_ws, const float* __restrict__ sp,
    float* __restrict__ edges, float* __restrict__ em1, float* __restrict__ em2)
{
  const int t = threadIdx.x;
  const int bid = blockIdx.x;
  const int b = bid >> 9;
  const int r = bid & 511;
  const int i0 = (r >> 2) << 3;
  const int j = ((r & 3) << 8) + t;

  // per-j ligand vector (loop-invariant)
  float dl[16];
  {
    const float4* dp = (const float4*)&dl_ws[((size_t)(b * NN + j)) << 4];
    const float4 a0 = dp[0], a1 = dp[1], a2 = dp[2], a3 = dp[3];
    dl[0] = a0.x; dl[1] = a0.y; dl[2] = a0.z; dl[3] = a0.w;
    dl[4] = a1.x; dl[5] = a1.y; dl[6] = a1.z; dl[7] = a1.w;
    dl[8] = a2.x; dl[9] = a2.y; dl[10] = a2.z; dl[11] = a2.w;
    dl[12] = a3.x; dl[13] = a3.y; dl[14] = a3.z; dl[15] = a3.w;
  }

  #pragma unroll 1
  for (int ii = 0; ii < 8; ++ii) {
    const int i = i0 + ii;
    const float d = dist[((size_t)(b * NN + i) << 10) + j];

    // v = sigmoid(d*softplus(ws)+bs) * data_ligand[b,j,:]
    float v[16];
    #pragma unroll
    for (int l = 0; l < 16; ++l)
      v[l] = dl[l] * fsig(fmaf(d, sp[l], bsv[l]));

    // h = v @ Wl1  (Wl1 via scalar loads -> SGPR operands)
    float h[64];
    #pragma unroll
    for (int c = 0; c < 64; ++c) h[c] = v[0] * Wl1[c];
    #pragma unroll
    for (int l = 1; l < 16; ++l) {
      #pragma unroll
      for (int c = 0; c < 64; ++c) h[c] = fmaf(v[l], Wl1[l * 64 + c], h[c]);
    }

    // exact gelu
    #pragma unroll
    for (int c = 0; c < 64; ++c) h[c] = gelu_f(h[c]);

    // o = gelu(h) @ Wl2
    float o[16];
    #pragma unroll
    for (int e = 0; e < 16; ++e) o[e] = h[0] * Wl2[e];
    #pragma unroll
    for (int c = 1; c < 64; ++c) {
      #pragma unroll
      for (int e = 0; e < 16; ++e) o[e] = fmaf(h[c], Wl2[c * 16 + e], o[e]);
    }

    const size_t base = (((size_t)(b * NN + i) << 10) + (size_t)j) << 4;
    {
      float4* ep = (float4*)&edges[base];
      ep[0] = make_float4(o[0], o[1], o[2], o[3]);
      ep[1] = make_float4(o[4], o[5], o[6], o[7]);
      ep[2] = make_float4(o[8], o[9], o[10], o[11]);
      ep[3] = make_float4(o[12], o[13], o[14], o[15]);
    }

    // emb1 = sigmoid(d*softplus(w1e)+b1e); emb2 = (d*softplus(w2e)+b2e)*0.25
    float p1[16], p2[16];
    #pragma unroll
    for (int e = 0; e < 16; ++e) {
      p1[e] = fsig(fmaf(d, sp[16 + e], b1e[e]));
      p2[e] = fmaf(d, sp[32 + e], b2e[e]) * 0.25f;
    }
    {
      float4* e1p = (float4*)&em1[base];
      e1p[0] = make_float4(p1[0], p1[1], p1[2], p1[3]);
      e1p[1] = make_float4(p1[4], p1[5], p1[6], p1[7]);
      e1p[2] = make_float4(p1[8], p1[9], p1[10], p1[11]);
      e1p[3] = make_float4(p1[12], p1[13], p1[14], p1[15]);
      float4* e2p = (float4*)&em2[base];
      e2p[0] = make_float4(p2[0], p2[1], p2[2], p2[3]);
      e2p[1] = make_float4(p2[4], p2[5], p2[6], p2[7]);
      e2p[2] = make_float4(p2[8], p2[9], p2[10], p2[11]);
      e2p[3] = make_float4(p2[12], p2[13], p2[14], p2[15]);
    }
  }
}

extern "C" void kernel_launch(void* const* d_in, const int* in_sizes, int n_in,
                              void* d_out, int out_size, void* d_ws, size_t ws_size,
                              hipStream_t stream)
{
  const float* x    = (const float*)d_in[0];
  const float* te   = (const float*)d_in[1];
  const float* dist = (const float*)d_in[2];
  const int*   ct   = (const int*)d_in[3];
  const float* scal = (const float*)d_in[4];
  const float* W1   = (const float*)d_in[5];
  const float* b1   = (const float*)d_in[6];
  const float* W2   = (const float*)d_in[7];
  const float* b2   = (const float*)d_in[8];
  const float* ctem = (const float*)d_in[9];
  const float* lng  = (const float*)d_in[10];
  const float* lnb  = (const float*)d_in[11];
  const float* wsv  = (const float*)d_in[12];
  const float* bsv  = (const float*)d_in[13];
  const float* w1e  = (const float*)d_in[14];
  const float* b1e  = (const float*)d_in[15];
  const float* w2e  = (const float*)d_in[16];
  const float* b2e  = (const float*)d_in[17];
  const float* Wl1  = (const float*)d_in[18];
  const float* Wl2  = (const float*)d_in[19];
  const int*   lig  = (const int*)d_in[20];

  float* out   = (float*)d_out;
  float* nf    = out;                    // (2,1024,256)
  float* edges = out + 524288;           // (2,1024,1024,16)
  float* em1   = out + 34078720;         // (2,1024,1024,16)
  float* em2   = out + 67633152;         // (2,1024,1024,16)

  float* dl_ws = (float*)d_ws;                       // (2,1024,16)
  float* sp_ws = dl_ws + (size_t)BB * NN * LL;       // 48 floats: sp(ws), sp(w1e), sp(w2e)

  hipLaunchKernelGGL(k_nf, dim3(256), dim3(256), 0, stream,
      x, te, ct, scal, W1, b1, W2, b2, ctem, lng, lnb, lig, wsv, w1e, w2e,
      dl_ws, sp_ws, nf);

  hipLaunchKernelGGL(k_edges, dim3(1024), dim3(256), 0, stream,
      dist, bsv, b1e, b2e, Wl1, Wl2, dl_ws, sp_ws, edges, em1, em2);
}

// Round 4
// 606.091 us; speedup vs baseline: 2.3289x; 2.3289x over previous
//
#include <hip/hip_runtime.h>
#include <math.h>

#define NN 1024
#define BB 2
#define GG 64
#define LL 16
#define ND 256
#define H1 1024
#define ED 16

// ---------- fast device math ----------
__device__ __forceinline__ float fsig(float x) {
  return __builtin_amdgcn_rcpf(1.0f + __builtin_amdgcn_exp2f(-1.44269504f * x));
}

__device__ __forceinline__ float erf_as(float x) {
  // Abramowitz-Stegun 7.1.26, branchless, |err| < 1.5e-7
  float ax = fabsf(x);
  float t = __builtin_amdgcn_rcpf(fmaf(0.3275911f, ax, 1.0f));
  float p = fmaf(1.061405429f, t, -1.453152027f);
  p = fmaf(p, t, 1.421413741f);
  p = fmaf(p, t, -0.284496736f);
  p = fmaf(p, t, 0.254829592f);
  p *= t;
  float ex = __builtin_amdgcn_exp2f(-1.44269504f * ax * ax);
  float r = fmaf(-p, ex, 1.0f);
  return copysignf(r, x);
}

__device__ __forceinline__ float gelu_f(float x) {
  return 0.5f * x * (1.0f + erf_as(0.70710678118f * x));
}

// ---------- K1: nf (FFN + ct_emb + LN), data_ligand, one-time param prep ----------
// identity: where(same, ffn(te*s), ffn(exp_t)) == ffn(exp_t) since exp_t==te*s when same.
// 1024 blocks x 2 positions: 4 blocks/CU for latency hiding (prev: 256 blocks = 1 wave/SIMD).
__global__ __launch_bounds__(256) void k_nf(
    const float* __restrict__ x, const float* __restrict__ te, const int* __restrict__ ct,
    const float* __restrict__ scal, const float* __restrict__ W1, const float* __restrict__ b1,
    const float* __restrict__ W2, const float* __restrict__ b2, const float* __restrict__ ctemb,
    const float* __restrict__ lng, const float* __restrict__ lnb, const int* __restrict__ lig,
    const float* __restrict__ wsv, const float* __restrict__ w1e, const float* __restrict__ w2e,
    const float* __restrict__ Wl1,
    float* __restrict__ dl_ws, float* __restrict__ sp_ws, float* __restrict__ w1t_ws,
    float* __restrict__ nf_out)
{
  __shared__ float s_exp[2 * 64];     // [p][g]
  __shared__ float s_h[H1 * 3];       // [c][p], stride 3 (gcd(3,32)=1 -> conflict-free writes)
  __shared__ float s_part[8 * 256];   // [w*2+p][oc]
  __shared__ float s_z[2 * 256];      // pre-LN

  const int t = threadIdx.x, bid = blockIdx.x;
  const int b = bid >> 9, n0 = (bid & 511) << 1;

  // one-time prep for K2 (block 0): softplus'd params + Wl1 transpose (w1t[c][l])
  if (bid == 0) {
    if (t < 48) {
      const float* src = (t < 16) ? wsv : (t < 32 ? w1e : w2e);
      float v = src[t & 15];
      sp_ws[t] = fmaxf(v, 0.0f) + log1pf(expf(-fabsf(v)));
    }
    for (int idx = t; idx < 1024; idx += 256)
      w1t_ws[idx] = Wl1[(idx & 15) * 64 + (idx >> 4)];
  }

  const int ct0 = ct[b * NN];

  // exp_t for 2 positions
  if (t < 128) {
    const int p = t >> 6, g = t & 63;
    const int n = n0 + p;
    const bool same = (ct[b * NN + n] == ct0);
    const float tv = te[(size_t)(b * NN + n) * GG + g];
    const float xv = x[(size_t)(b * NN + n) * GG + g];
    const float sc = scal[g];
    s_exp[p * 64 + g] = (same ? tv : tv + xv) * (sc * sc);
  }
  __syncthreads();

  // data_ligand -> workspace
  if (t < 32) {
    const int p = t >> 4, l = t & 15;
    const int4 li = ((const int4*)lig)[l];
    const float gm0 = 0.5f * (s_exp[p * 64 + li.x] + s_exp[p * 64 + li.y]);
    const float gm1 = 0.5f * (s_exp[p * 64 + li.z] + s_exp[p * 64 + li.w]);
    dl_ws[((size_t)(b * NN + n0 + p) << 4) + l] = sqrtf(gm0 * gm1);
  }

  // GEMM1: thread t owns channels {t, t+256, t+512, t+768}, both positions
  float a00 = 0, a01 = 0, a02 = 0, a03 = 0, a10 = 0, a11 = 0, a12 = 0, a13 = 0;
  for (int g = 0; g < 64; ++g) {
    const float w0 = W1[(size_t)g * H1 + t];
    const float w1 = W1[(size_t)g * H1 + t + 256];
    const float w2 = W1[(size_t)g * H1 + t + 512];
    const float w3 = W1[(size_t)g * H1 + t + 768];
    const float e0 = s_exp[g];          // broadcast
    const float e1 = s_exp[64 + g];
    a00 = fmaf(e0, w0, a00); a01 = fmaf(e0, w1, a01);
    a02 = fmaf(e0, w2, a02); a03 = fmaf(e0, w3, a03);
    a10 = fmaf(e1, w0, a10); a11 = fmaf(e1, w1, a11);
    a12 = fmaf(e1, w2, a12); a13 = fmaf(e1, w3, a13);
  }
  {
    const float bk0 = b1[t], bk1 = b1[t + 256], bk2 = b1[t + 512], bk3 = b1[t + 768];
    s_h[t * 3 + 0]          = gelu_f(a00 + bk0);
    s_h[t * 3 + 1]          = gelu_f(a10 + bk0);
    s_h[(t + 256) * 3 + 0]  = gelu_f(a01 + bk1);
    s_h[(t + 256) * 3 + 1]  = gelu_f(a11 + bk1);
    s_h[(t + 512) * 3 + 0]  = gelu_f(a02 + bk2);
    s_h[(t + 512) * 3 + 1]  = gelu_f(a12 + bk2);
    s_h[(t + 768) * 3 + 0]  = gelu_f(a03 + bk3);
    s_h[(t + 768) * 3 + 1]  = gelu_f(a13 + bk3);
  }
  __syncthreads();

  // GEMM2: wave w takes c-slice [w*256, w*256+256), lanes own 4 out-channels, both positions
  const int w = t >> 6, lane = t & 63, oc0 = lane << 2, cbase = w << 8;
  float z00 = 0, z01 = 0, z02 = 0, z03 = 0, z10 = 0, z11 = 0, z12 = 0, z13 = 0;
  for (int c = cbase; c < cbase + 256; ++c) {
    const float4 wv = *(const float4*)&W2[(size_t)c * ND + oc0];
    const float h0 = s_h[c * 3 + 0];    // broadcast
    const float h1 = s_h[c * 3 + 1];
    z00 = fmaf(h0, wv.x, z00); z01 = fmaf(h0, wv.y, z01);
    z02 = fmaf(h0, wv.z, z02); z03 = fmaf(h0, wv.w, z03);
    z10 = fmaf(h1, wv.x, z10); z11 = fmaf(h1, wv.y, z11);
    z12 = fmaf(h1, wv.z, z12); z13 = fmaf(h1, wv.w, z13);
  }
  *(float4*)&s_part[((w << 1) + 0) * 256 + oc0] = make_float4(z00, z01, z02, z03);
  *(float4*)&s_part[((w << 1) + 1) * 256 + oc0] = make_float4(z10, z11, z12, z13);
  __syncthreads();

  // reduce partials + bias + ct_emb
  #pragma unroll
  for (int p = 0; p < 2; ++p) {
    const float v = s_part[(0 + p) * 256 + t] + s_part[(2 + p) * 256 + t] +
                    s_part[(4 + p) * 256 + t] + s_part[(6 + p) * 256 + t];
    const int cc = ct[b * NN + n0 + p];
    s_z[p * 256 + t] = v + b2[t] + ctemb[(size_t)cc * ND + t];
  }
  __syncthreads();

  // LayerNorm: wave 0 -> position 0, wave 1 -> position 1
  if (w < 2) {
    const float4 v4 = *(const float4*)&s_z[(w << 8) + (lane << 2)];
    float s = v4.x + v4.y + v4.z + v4.w;
    float sq = v4.x * v4.x + v4.y * v4.y + v4.z * v4.z + v4.w * v4.w;
    #pragma unroll
    for (int off = 1; off < 64; off <<= 1) {
      s += __shfl_xor(s, off);
      sq += __shfl_xor(sq, off);
    }
    const float m = s * (1.0f / 256.0f);
    const float var = sq * (1.0f / 256.0f) - m * m;
    const float rstd = rsqrtf(var + 1e-5f);
    const float4 g4 = *(const float4*)&lng[lane << 2];
    const float4 b4 = *(const float4*)&lnb[lane << 2];
    float4 o;
    o.x = (v4.x - m) * rstd * g4.x + b4.x;
    o.y = (v4.y - m) * rstd * g4.y + b4.y;
    o.z = (v4.z - m) * rstd * g4.z + b4.z;
    o.w = (v4.w - m) * rstd * g4.w + b4.w;
    *(float4*)&nf_out[((size_t)(b * NN + n0 + w) << 8) + (lane << 2)] = o;
  }
}

// ---------- K2: edges + emb1 + emb2 ----------
// P=4 i-rows per thread; loop interchanged so each weight s_load is reused 4x
// (32 scalar loads per channel c amortized over 4*(16+16) FMAs -> 32x fewer s_loads
//  than streaming the full weight set per position).
__global__ __launch_bounds__(256, 3) void k_edges(
    const float* __restrict__ dist, const float* __restrict__ bsv,
    const float* __restrict__ b1e, const float* __restrict__ b2e,
    const float* __restrict__ w1t, const float* __restrict__ Wl2,
    const float* __restrict__ dl_ws, const float* __restrict__ sp,
    float* __restrict__ edges, float* __restrict__ em1, float* __restrict__ em2)
{
  const int t = threadIdx.x, bid = blockIdx.x;
  const int b = bid >> 10, r = bid & 1023;
  const int i0 = (r >> 2) << 2;          // 4 i-rows per block
  const int j = ((r & 3) << 8) + t;

  // per-j ligand vector
  float dl[16];
  {
    const float4* dp = (const float4*)&dl_ws[((size_t)(b * NN + j)) << 4];
    const float4 a0 = dp[0], a1 = dp[1], a2 = dp[2], a3 = dp[3];
    dl[0] = a0.x; dl[1] = a0.y; dl[2] = a0.z; dl[3] = a0.w;
    dl[4] = a1.x; dl[5] = a1.y; dl[6] = a1.z; dl[7] = a1.w;
    dl[8] = a2.x; dl[9] = a2.y; dl[10] = a2.z; dl[11] = a2.w;
    dl[12] = a3.x; dl[13] = a3.y; dl[14] = a3.z; dl[15] = a3.w;
  }

  float d[4];
  #pragma unroll
  for (int p = 0; p < 4; ++p)
    d[p] = dist[((size_t)(b * NN + i0 + p) << 10) + j];

  // emb1 / emb2 first (frees their registers before the FFN)
  #pragma unroll
  for (int p = 0; p < 4; ++p) {
    const size_t base = (((size_t)(b * NN + i0 + p) << 10) + (size_t)j) << 4;
    float q1[16], q2[16];
    #pragma unroll
    for (int e = 0; e < 16; ++e) {
      q1[e] = fsig(fmaf(d[p], sp[16 + e], b1e[e]));
      q2[e] = fmaf(d[p], sp[32 + e], b2e[e]) * 0.25f;
    }
    float4* e1p = (float4*)&em1[base];
    e1p[0] = make_float4(q1[0], q1[1], q1[2], q1[3]);
    e1p[1] = make_float4(q1[4], q1[5], q1[6], q1[7]);
    e1p[2] = make_float4(q1[8], q1[9], q1[10], q1[11]);
    e1p[3] = make_float4(q1[12], q1[13], q1[14], q1[15]);
    float4* e2p = (float4*)&em2[base];
    e2p[0] = make_float4(q2[0], q2[1], q2[2], q2[3]);
    e2p[1] = make_float4(q2[4], q2[5], q2[6], q2[7]);
    e2p[2] = make_float4(q2[8], q2[9], q2[10], q2[11]);
    e2p[3] = make_float4(q2[12], q2[13], q2[14], q2[15]);
  }

  // v[p][l] = dl[l] * sigmoid(d[p]*softplus(ws)[l] + bs[l])
  float v[4][16];
  #pragma unroll
  for (int p = 0; p < 4; ++p)
    #pragma unroll
    for (int l = 0; l < 16; ++l)
      v[p][l] = dl[l] * fsig(fmaf(d[p], sp[l], bsv[l]));

  // FFN: o[p] = gelu(v[p] @ Wl1) @ Wl2, channel-by-channel
  float o[4][16];
  #pragma unroll
  for (int p = 0; p < 4; ++p)
    #pragma unroll
    for (int e = 0; e < 16; ++e) o[p][e] = 0.0f;

  #pragma unroll 2
  for (int c = 0; c < 64; ++c) {
    const float* wc  = w1t + (c << 4);   // Wl1 column c (pre-transposed, contiguous s_loads)
    const float* w2c = Wl2 + (c << 4);   // Wl2 row c (contiguous s_loads)
    #pragma unroll
    for (int p = 0; p < 4; ++p) {
      float hc = v[p][0] * wc[0];
      #pragma unroll
      for (int l = 1; l < 16; ++l) hc = fmaf(v[p][l], wc[l], hc);
      const float g = gelu_f(hc);
      #pragma unroll
      for (int e = 0; e < 16; ++e) o[p][e] = fmaf(g, w2c[e], o[p][e]);
    }
  }

  #pragma unroll
  for (int p = 0; p < 4; ++p) {
    const size_t base = (((size_t)(b * NN + i0 + p) << 10) + (size_t)j) << 4;
    float4* ep = (float4*)&edges[base];
    ep[0] = make_float4(o[p][0], o[p][1], o[p][2], o[p][3]);
    ep[1] = make_float4(o[p][4], o[p][5], o[p][6], o[p][7]);
    ep[2] = make_float4(o[p][8], o[p][9], o[p][10], o[p][11]);
    ep[3] = make_float4(o[p][12], o[p][13], o[p][14], o[p][15]);
  }
}

extern "C" void kernel_launch(void* const* d_in, const int* in_sizes, int n_in,
                              void* d_out, int out_size, void* d_ws, size_t ws_size,
                              hipStream_t stream)
{
  const float* x    = (const float*)d_in[0];
  const float* te   = (const float*)d_in[1];
  const float* dist = (const float*)d_in[2];
  const int*   ct   = (const int*)d_in[3];
  const float* scal = (const float*)d_in[4];
  const float* W1   = (const float*)d_in[5];
  const float* b1   = (const float*)d_in[6];
  const float* W2   = (const float*)d_in[7];
  const float* b2   = (const float*)d_in[8];
  const float* ctem = (const float*)d_in[9];
  const float* lng  = (const float*)d_in[10];
  const float* lnb  = (const float*)d_in[11];
  const float* wsv  = (const float*)d_in[12];
  const float* bsv  = (const float*)d_in[13];
  const float* w1e  = (const float*)d_in[14];
  const float* b1e  = (const float*)d_in[15];
  const float* w2e  = (const float*)d_in[16];
  const float* b2e  = (const float*)d_in[17];
  const float* Wl1  = (const float*)d_in[18];
  const float* Wl2  = (const float*)d_in[19];
  const int*   lig  = (const int*)d_in[20];

  float* out   = (float*)d_out;
  float* nf    = out;                    // (2,1024,256)
  float* edges = out + 524288;           // (2,1024,1024,16)
  float* em1   = out + 34078720;         // (2,1024,1024,16)
  float* em2   = out + 67633152;         // (2,1024,1024,16)

  float* dl_ws  = (float*)d_ws;                       // 32768 floats
  float* sp_ws  = dl_ws + (size_t)BB * NN * LL;       // 48 floats
  float* w1t_ws = sp_ws + 48;                         // 1024 floats (Wl1 transposed)

  hipLaunchKernelGGL(k_nf, dim3(1024), dim3(256), 0, stream,
      x, te, ct, scal, W1, b1, W2, b2, ctem, lng, lnb, lig, wsv, w1e, w2e, Wl1,
      dl_ws, sp_ws, w1t_ws, nf);

  hipLaunchKernelGGL(k_edges, dim3(2048), dim3(256), 0, stream,
      dist, bsv, b1e, b2e, w1t_ws, Wl2, dl_ws, sp_ws, edges, em1, em2);
}